// Round 1
// baseline (786.486 us; speedup 1.0000x reference)
//
#include <hip/hip_runtime.h>

// uDTW forward DP on MI355X.
// B=32 batches, N=M=512. One block per batch, thread t owns row r=t (cell i=t+1
// of every anti-diagonal). 1023 wavefront steps with one __syncthreads each.
// Own R/D history in registers; only left-neighbor {R, Dv} goes through a
// 4-slot LDS ring (float2 per thread per step).
// Sig is only needed at 4 elements (the recursion never reads S).

constexpr int N = 512;
constexpr int M = 512;
constexpr int BATCH = 32;
constexpr float BIGF = 1e30f;
constexpr float ALPHA = 1.0f;   // 1/GAMMA, GAMMA=1

__global__ __launch_bounds__(512)
void softdtw_fwd(const float* __restrict__ D,
                 const float* __restrict__ Sig,
                 float* __restrict__ out) {
    const int b = blockIdx.x;
    const int t = threadIdx.x;              // 0..511 ; i = t+1 ; row r = t
    const float* Drow = D + ((size_t)b * N + t) * M;

    // ring of published {newR, ddd} per thread; slot = d & 3
    __shared__ float2 edge[4][512];

    // init slots for diag d=0 and d=1:
    //   R-diag entries for i>=1 are BIG on both; D-diag entries are 0.
    edge[0][t] = make_float2(BIGF, 0.0f);
    edge[1][t] = make_float2(BIGF, 0.0f);

    // own history (diag d-1): R and Dv of my cell
    float rA = BIGF;
    float dA = 0.0f;

    // rolling float4 prefetch of my row of D (column c = d - t - 2)
    float4 q_cur = *(const float4*)(Drow + 0);   // c = 0..3
    float4 q_nxt = *(const float4*)(Drow + 4);   // c = 4..7

    // Sig contributes only through 4 elements at the final cell
    float sgA = 0.f, sg0 = 0.f, sg1 = 0.f, sg2 = 0.f;
    if (t == N - 1) {
        const float* Sb = Sig + (size_t)b * N * M;
        sgA = Sb[(size_t)(N-1) * M + (M-1)];   // Sig[511,511]
        sg0 = Sb[(size_t)(N-2) * M + (M-2)];   // Sig[510,510]
        sg1 = Sb[(size_t)(N-2) * M + (M-1)];   // Sig[510,511]
        sg2 = Sb[(size_t)(N-1) * M + (M-2)];   // Sig[511,510]
    }
    __syncthreads();

    float outR = 0.f, outS = 0.f;
    const int tm1 = (t == 0) ? 0 : (t - 1);

    for (int d = 2; d <= N + M; ++d) {
        const int c = d - t - 2;             // my D column this step (j = c+1)

        // left-neighbor values at diag d-1 and d-2
        float2 n1 = edge[(d - 1) & 3][tm1];
        float2 n2 = edge[(d - 2) & 3][tm1];
        float nR1 = n1.x, nD1 = n1.y;
        float nR2 = n2.x, nD2 = n2.y;
        if (t == 0) {                        // virtual index i=0 (padded row)
            nR1 = BIGF;
            nR2 = (d == 2) ? 0.0f : BIGF;    // R[0,0]=0 only on diag 0
            nD1 = 0.0f;
            nD2 = 0.0f;
        }

        // my D diagonal value (0 outside the matrix, per reference diag())
        float ddd = 0.0f;
        if (c >= 0) {
            const int ph = c & 3;
            float v = (ph == 0) ? q_cur.x
                    : (ph == 1) ? q_cur.y
                    : (ph == 2) ? q_cur.z
                    :             q_cur.w;
            if (c <= M - 1) ddd = v;
            if (ph == 3 && c < M - 1) {      // rotate, prefetch next quad
                q_cur = q_nxt;
                const int cb = (c + 5 <= M - 4) ? (c + 5) : (M - 4);
                q_nxt = *(const float4*)(Drow + cb);
            }
        }

        const bool valid = (c >= 0) && (c <= M - 1);

        // softmin weights from predecessors' R (no max-subtraction needed:
        // valid cells always have >=1 finite pred; rr in [-3,0] or -1e30)
        const float e0 = __expf(-ALPHA * nR2);   // pred (i-1, j-1)
        const float e1 = __expf(-ALPHA * nR1);   // pred (i-1, j)
        const float e2 = __expf(-ALPHA * rA);    // pred (i,   j-1)
        const float inv = __builtin_amdgcn_rcpf(e0 + e1 + e2);

        const float newR =
            valid ? (ddd + inv * (e0 * nD2 + e1 * nD1 + e2 * dA)) : BIGF;

        if (d == N + M && t == N - 1) {      // final cell (512,512)
            outR = newR;
            outS = sgA + inv * (e0 * sg0 + e1 * sg1 + e2 * sg2);
        }

        // publish my values for the right neighbor; rotate own history
        edge[d & 3][t] = make_float2(newR, ddd);
        rA = newR;
        dA = ddd;
        __syncthreads();
    }

    if (t == N - 1) {
        out[b] = outR;            // rlast[:, n]
        out[BATCH + b] = outS;    // slast[:, n]
    }
}

extern "C" void kernel_launch(void* const* d_in, const int* in_sizes, int n_in,
                              void* d_out, int out_size, void* d_ws, size_t ws_size,
                              hipStream_t stream) {
    const float* D   = (const float*)d_in[0];
    const float* Sig = (const float*)d_in[1];
    float* out = (float*)d_out;
    softdtw_fwd<<<dim3(BATCH), dim3(512), 0, stream>>>(D, Sig, out);
}

// Round 2
// 577.988 us; speedup vs baseline: 1.3607x; 1.3607x over previous
//
#include <hip/hip_runtime.h>

// uDTW forward DP, skewed-wave pipeline.
// B=32 batches, N=M=512. One block (512 thr = 8 waves) per batch; thread t owns
// row t (cell i=t+1 on every anti-diagonal d=2..1024).
// Cross-lane neighbor data via __shfl_up within a wave (no barrier); wave
// boundary (lane 63 -> next wave lane 0) via a 64-slot LDS ring. Waves are
// skewed: wave w computes diagonal-burst B (K=16 diags) at phase p=w+B, so
// only ONE __syncthreads per phase (71 total vs 1023 in round 0).
// We carry exp(-R) (not R) across lanes so each cell does exactly one exp and
// the neighbor's exp is ready-made (keeps exp out of the cross-lane chain).
// Sig enters only through 4 elements at the final cell (recursion never reads S).

constexpr int N = 512;
constexpr int M = 512;
constexpr int BATCH = 32;
constexpr int NM = N + M;                  // 1024; diags d = 2..NM (1023 steps)
constexpr int K = 16;                      // diagonals per burst
constexpr int NB = (NM - 1 + K - 1) / K;   // 64 bursts
constexpr int RING = 4 * K;                // 64-slot ring (4 bursts) per wave
constexpr float BIGF = 1e30f;

__global__ __launch_bounds__(512)
void softdtw_fwd(const float* __restrict__ D,
                 const float* __restrict__ Sig,
                 float* __restrict__ out) {
  const int b = blockIdx.x;
  const int t = threadIdx.x;           // row r = t, cell i = t+1
  const int w = t >> 6;                // wave 0..7
  const int lane = t & 63;
  const float* Drow = D + ((size_t)b * N + t) * M;

  // lane-63 boundary ring: edge[w][d & 63] = (exp(-R), Ddiag) of row 64w+63 at diag d
  __shared__ float2 edge[8][RING];

  if (t < 8) {                          // slot for diag 1 read by burst 0
    edge[t][0] = make_float2(0.f, 0.f);
    edge[t][1] = make_float2(0.f, 0.f);
  }

  // rolling window of my D row: Q0 covers current quad, prefetch depth 5
  // (load issued ~16 steps before use -> covers HBM latency at ~100 cyc/step)
  float4 Q0 = *(const float4*)(Drow + 0);
  float4 Q1 = *(const float4*)(Drow + 4);
  float4 Q2 = *(const float4*)(Drow + 8);
  float4 Q3 = *(const float4*)(Drow + 12);
  float4 Q4 = *(const float4*)(Drow + 16);

  // carried state: own cell at d-1, neighbor (i-1) at d-2
  float eSelf = 0.f, dSelf = 0.f;                 // exp(-R[i,d-1]), Ddiag[i,d-1]
  float eN2 = (t == 0) ? 1.f : 0.f, dN2 = 0.f;    // exp(-R[i-1,d-2]) (R[0,0]=0), Ddiag

  // Sig contributes only via 4 elements at the final cell
  float sgA = 0.f, sg0 = 0.f, sg1 = 0.f, sg2 = 0.f;
  if (t == N - 1) {
    const float* Sb = Sig + (size_t)b * N * M;
    sgA = Sb[(size_t)(N - 1) * M + (M - 1)];
    sg0 = Sb[(size_t)(N - 2) * M + (M - 2)];
    sg1 = Sb[(size_t)(N - 2) * M + (M - 1)];
    sg2 = Sb[(size_t)(N - 1) * M + (M - 2)];
  }
  __syncthreads();

  const int P = NB + 7;                 // phases; wave w active for p in [w, w+NB)
  for (int p = 0; p < P; ++p) {
    const int B = p - w;
    if (B >= 0 && B < NB) {
      const int d0 = 2 + B * K;
      // preload neighbor-wave boundary values for diags d0-1 .. d0+K-2
      float2 nb[K];
      if (w > 0) {
        #pragma unroll
        for (int k = 0; k < K; ++k)
          nb[k] = edge[w - 1][(d0 - 1 + k) & (RING - 1)];
      } else {
        #pragma unroll
        for (int k = 0; k < K; ++k) nb[k] = make_float2(0.f, 0.f);  // virtual row 0
      }
      #pragma unroll
      for (int k = 0; k < K; ++k) {
        const int d = d0 + k;
        if (d <= NM) {
          const int c = d - t - 2;      // my D column this step (j = c+1)
          // my D diagonal value (0 outside matrix, per reference diag())
          float ddd = 0.f;
          if (c >= 0) {
            const int ph = c & 3;
            float v = (ph == 0) ? Q0.x : (ph == 1) ? Q0.y : (ph == 2) ? Q0.z : Q0.w;
            if (c <= M - 1) ddd = v;
            if (ph == 3 && c < M - 1) {
              Q0 = Q1; Q1 = Q2; Q2 = Q3; Q3 = Q4;
              int cb = c + 17; if (cb > M - 4) cb = M - 4;
              Q4 = *(const float4*)(Drow + cb);
            }
          }
          // neighbor (i-1) values at diag d-1: in-wave via shuffle, boundary via nb[]
          float sE = __shfl_up(eSelf, 1);
          float sD = __shfl_up(dSelf, 1);
          if (lane == 0) { sE = nb[k].x; sD = nb[k].y; }
          const float e0 = eN2, e1 = sE, e2 = eSelf;
          const float sum = e0 + e1 + e2;
          const float inv = __builtin_amdgcn_rcpf(sum);
          const float num = fmaf(e0, dN2, fmaf(e1, sD, e2 * dSelf));
          const bool valid = (c >= 0) && (c < M);
          const float newR = valid ? fmaf(inv, num, ddd) : BIGF;
          const float newE = __expf(-newR);   // exp(-BIG) underflows to 0: correct
          if (d == NM && t == N - 1) {        // final cell (512,512)
            out[b] = newR;                                        // rlast[:, n]
            out[BATCH + b] = sgA + inv * (e0 * sg0 + e1 * sg1 + e2 * sg2);  // slast
          }
          // rotate carries
          eN2 = e1; dN2 = sD;
          eSelf = newE; dSelf = ddd;
          // publish wave boundary for next wave
          if (lane == 63 && w < 7)
            edge[w][d & (RING - 1)] = make_float2(newE, ddd);
        }
      }
    }
    __syncthreads();
  }
}

extern "C" void kernel_launch(void* const* d_in, const int* in_sizes, int n_in,
                              void* d_out, int out_size, void* d_ws, size_t ws_size,
                              hipStream_t stream) {
  const float* D   = (const float*)d_in[0];
  const float* Sig = (const float*)d_in[1];
  float* out = (float*)d_out;
  softdtw_fwd<<<dim3(BATCH), dim3(512), 0, stream>>>(D, Sig, out);
}

// Round 3
// 556.458 us; speedup vs baseline: 1.4134x; 1.0387x over previous
//
#include <hip/hip_runtime.h>

// uDTW forward DP, skewed-wave pipeline, R2: cross-lane hop via DPP wave_shr:1
// instead of __shfl_up (ds_bpermute). The per-step dependent chain was
// dominated by the ~120+cyc LDS-class bpermute latency; DPP is a VALU-latency
// (~4 cyc) lane shift, taking the cross-lane move out of the critical path.
// Structure otherwise identical to R1 (validated, absmax 0.0):
//   B=32 batches, 1 block (8 waves) per batch, thread t owns row t.
//   Waves skewed in K=16-diag bursts, one __syncthreads per phase (71 total).
//   Wave boundary (lane63 -> next wave lane0) via 64-slot LDS ring.
//   We carry exp(-R), so each cell does exactly one exp.
//   Sig enters only via 4 elements at the final cell.

constexpr int N = 512;
constexpr int M = 512;
constexpr int BATCH = 32;
constexpr int NM = N + M;                  // 1024; diags d = 2..NM (1023 steps)
constexpr int K = 16;                      // diagonals per burst
constexpr int NB = (NM - 1 + K - 1) / K;   // 64 bursts
constexpr int RING = 4 * K;                // 64-slot ring (4 bursts) per wave
constexpr float BIGF = 1e30f;

__device__ __forceinline__ float lane_shr1(float x) {
  // lane n gets lane n-1's x; lane 0 gets 0 (overridden by caller anyway).
  // DPP ctrl 0x138 = wave_shr:1 (gfx9/CDNA lineage).
  return __int_as_float(
      __builtin_amdgcn_update_dpp(0, __float_as_int(x), 0x138, 0xf, 0xf, true));
}

__global__ __launch_bounds__(512)
void softdtw_fwd(const float* __restrict__ D,
                 const float* __restrict__ Sig,
                 float* __restrict__ out) {
  const int b = blockIdx.x;
  const int t = threadIdx.x;           // row r = t, cell i = t+1
  const int w = t >> 6;                // wave 0..7
  const int lane = t & 63;
  const bool l0 = (lane == 0);
  const float* Drow = D + ((size_t)b * N + t) * M;

  // lane-63 boundary ring: edge[w][d & 63] = (exp(-R), Ddiag) of row 64w+63 at diag d
  __shared__ float2 edge[8][RING];

  if (t < 8) {                          // slots for diags 0,1 read by burst 0
    edge[t][0] = make_float2(0.f, 0.f);
    edge[t][1] = make_float2(0.f, 0.f);
  }

  // rolling window of my D row, prefetch depth 5 (load ~16 steps before use)
  float4 Q0 = *(const float4*)(Drow + 0);
  float4 Q1 = *(const float4*)(Drow + 4);
  float4 Q2 = *(const float4*)(Drow + 8);
  float4 Q3 = *(const float4*)(Drow + 12);
  float4 Q4 = *(const float4*)(Drow + 16);

  // carried state: own cell at d-1, neighbor (i-1) at d-2
  float eSelf = 0.f, dSelf = 0.f;                 // exp(-R[i,d-1]), Ddiag[i,d-1]
  float eN2 = (t == 0) ? 1.f : 0.f, dN2 = 0.f;    // exp(-R[i-1,d-2]) (R[0,0]=0), Ddiag

  // Sig contributes only via 4 elements at the final cell
  float sgA = 0.f, sg0 = 0.f, sg1 = 0.f, sg2 = 0.f;
  if (t == N - 1) {
    const float* Sb = Sig + (size_t)b * N * M;
    sgA = Sb[(size_t)(N - 1) * M + (M - 1)];
    sg0 = Sb[(size_t)(N - 2) * M + (M - 2)];
    sg1 = Sb[(size_t)(N - 2) * M + (M - 1)];
    sg2 = Sb[(size_t)(N - 1) * M + (M - 2)];
  }
  __syncthreads();

  const int P = NB + 7;                 // phases; wave w active for p in [w, w+NB)
  for (int p = 0; p < P; ++p) {
    const int B = p - w;
    if (B >= 0 && B < NB) {
      const int d0 = 2 + B * K;
      // preload neighbor-wave boundary values for diags d0-1 .. d0+K-2
      float2 nb[K];
      if (w > 0) {
        #pragma unroll
        for (int k = 0; k < K; ++k)
          nb[k] = edge[w - 1][(d0 - 1 + k) & (RING - 1)];
      } else {
        #pragma unroll
        for (int k = 0; k < K; ++k) nb[k] = make_float2(0.f, 0.f);  // virtual row 0
      }
      #pragma unroll
      for (int k = 0; k < K; ++k) {
        const int d = d0 + k;
        if (d <= NM) {
          const int c = d - t - 2;      // my D column this step (j = c+1)
          // my D diagonal value (0 outside matrix, per reference diag())
          float ddd = 0.f;
          if (c >= 0) {
            const int ph = c & 3;
            float v = (ph == 0) ? Q0.x : (ph == 1) ? Q0.y : (ph == 2) ? Q0.z : Q0.w;
            if (c <= M - 1) ddd = v;
            if (ph == 3 && c < M - 1) {
              Q0 = Q1; Q1 = Q2; Q2 = Q3; Q3 = Q4;
              int cb = c + 17; if (cb > M - 4) cb = M - 4;
              Q4 = *(const float4*)(Drow + cb);
            }
          }
          // neighbor (i-1) values at diag d-1: in-wave via DPP, boundary via nb[]
          float sE = lane_shr1(eSelf);
          float sD = lane_shr1(dSelf);
          if (l0) { sE = nb[k].x; sD = nb[k].y; }
          const float e0 = eN2, e1 = sE, e2 = eSelf;
          const float sum = (e0 + e2) + e1;      // e1 arrives latest (dpp path)
          const float inv = __builtin_amdgcn_rcpf(sum);
          const float num = fmaf(e0, dN2, fmaf(e1, sD, e2 * dSelf));
          const bool valid = (c >= 0) && (c < M);
          const float newR = valid ? fmaf(inv, num, ddd) : BIGF;
          const float newE = __expf(-newR);   // exp(-BIG) underflows to 0: correct
          if (d == NM && t == N - 1) {        // final cell (512,512)
            out[b] = newR;                                        // rlast[:, n]
            out[BATCH + b] = sgA + inv * (e0 * sg0 + e1 * sg1 + e2 * sg2);  // slast
          }
          // rotate carries
          eN2 = e1; dN2 = sD;
          eSelf = newE; dSelf = ddd;
          // publish wave boundary for next wave
          if (lane == 63 && w < 7)
            edge[w][d & (RING - 1)] = make_float2(newE, ddd);
        }
      }
    }
    __syncthreads();
  }
}

extern "C" void kernel_launch(void* const* d_in, const int* in_sizes, int n_in,
                              void* d_out, int out_size, void* d_ws, size_t ws_size,
                              hipStream_t stream) {
  const float* D   = (const float*)d_in[0];
  const float* Sig = (const float*)d_in[1];
  float* out = (float*)d_out;
  softdtw_fwd<<<dim3(BATCH), dim3(512), 0, stream>>>(D, Sig, out);
}

// Round 4
// 401.945 us; speedup vs baseline: 1.9567x; 1.3844x over previous
//
#include <hip/hip_runtime.h>

// uDTW forward DP, skewed-wave pipeline, R3: kill the suspected scratch spill.
// R2's VGPR_Count=44 < live set (~52+) => nb[16] array likely in scratch, one
// ~200-400cyc scratch_load inside every serial DP step (fits 540 cyc/step).
// Changes vs R2 (structure & numerics otherwise identical, absmax was 0.0):
//  - k-loop has NO runtime guard (d>NM computed harmlessly), constant trip,
//    so #pragma unroll + SROA promote nbv[] to registers.
//  - __launch_bounds__(512,2): VGPR cap 256 (occupancy irrelevant: 32 blocks).
//  - chain shaved: carry exp2-domain, pre-scale num/ddd by -log2e off-chain,
//    mask invalid AFTER exp (sum==0 -> rcp=inf -> NaN must be masked).

constexpr int N = 512;
constexpr int M = 512;
constexpr int BATCH = 32;
constexpr int NM = N + M;                  // 1024; diags d = 2..NM
constexpr int K = 16;                      // diagonals per burst
constexpr int NB = 64;                     // bursts (covers d=2..1025)
constexpr int RING = 64;                   // edge ring slots per wave
constexpr float BIGF = 1e30f;
constexpr float NL2E = -1.4426950408889634f;   // -log2(e)

__device__ __forceinline__ float lane_shr1(float x) {
  // lane n gets lane n-1's x; lane 0 gets 0 (overridden by caller).
  return __int_as_float(
      __builtin_amdgcn_update_dpp(0, __float_as_int(x), 0x138, 0xf, 0xf, true));
}

__global__ __launch_bounds__(512, 2)
void softdtw_fwd(const float* __restrict__ D,
                 const float* __restrict__ Sig,
                 float* __restrict__ out) {
  const int b = blockIdx.x;
  const int t = threadIdx.x;           // row r = t, cell i = t+1
  const int w = t >> 6;                // wave 0..7
  const int lane = t & 63;
  const bool l0 = (lane == 0);
  const float* Drow = D + ((size_t)b * N + t) * M;

  // edge[w][d & 63] = (exp(-R), Ddiag) of row 64w+63 at diag d
  __shared__ float2 edge[8][RING];

  if (t < 8) {                          // slots for diags 0,1 read by burst 0
    edge[t][0] = make_float2(0.f, 0.f);
    edge[t][1] = make_float2(0.f, 0.f);
  }

  // rolling window of my D row, prefetch depth 5
  float4 Q0 = *(const float4*)(Drow + 0);
  float4 Q1 = *(const float4*)(Drow + 4);
  float4 Q2 = *(const float4*)(Drow + 8);
  float4 Q3 = *(const float4*)(Drow + 12);
  float4 Q4 = *(const float4*)(Drow + 16);

  // carried state: own cell at d-1, neighbor (i-1) at d-2
  float eSelf = 0.f, dSelf = 0.f;                 // exp(-R[i,d-1]), Ddiag
  float eN2 = (t == 0) ? 1.f : 0.f, dN2 = 0.f;    // exp(-R[i-1,d-2]) (R[0,0]=0)

  // Sig contributes only via 4 elements at the final cell
  float sgA = 0.f, sg0 = 0.f, sg1 = 0.f, sg2 = 0.f;
  if (t == N - 1) {
    const float* Sb = Sig + (size_t)b * N * M;
    sgA = Sb[(size_t)(N - 1) * M + (M - 1)];
    sg0 = Sb[(size_t)(N - 2) * M + (M - 2)];
    sg1 = Sb[(size_t)(N - 2) * M + (M - 1)];
    sg2 = Sb[(size_t)(N - 1) * M + (M - 2)];
  }
  __syncthreads();

  const int P = NB + 7;                 // wave w active for p in [w, w+NB)
  for (int p = 0; p < P; ++p) {
    const int B = p - w;
    if (B >= 0 && B < NB) {
      const int d0 = 2 + B * K;
      // neighbor-wave boundary values for diags d0-1 .. d0+K-2 (wave-uniform)
      float2 nbv[K];
      if (w > 0) {
        #pragma unroll
        for (int k = 0; k < K; ++k)
          nbv[k] = edge[w - 1][(d0 - 1 + k) & (RING - 1)];
      } else {
        #pragma unroll
        for (int k = 0; k < K; ++k) nbv[k] = make_float2(0.f, 0.f);
      }
      #pragma unroll
      for (int k = 0; k < K; ++k) {     // NO runtime guard: constant trip count
        const int d = d0 + k;
        const int c = d - t - 2;        // my D column this step (j = c+1)
        const bool valid = (c >= 0) && (c < M);
        // my D diagonal value (0 outside matrix)
        float ddd = 0.f;
        {
          const int ph = c & 3;
          float v = (ph == 0) ? Q0.x : (ph == 1) ? Q0.y : (ph == 2) ? Q0.z : Q0.w;
          if (valid) ddd = v;
          if (c >= 0 && ph == 3 && c < M - 1) {
            Q0 = Q1; Q1 = Q2; Q2 = Q3; Q3 = Q4;
            int cb = c + 17; if (cb > M - 4) cb = M - 4;
            Q4 = *(const float4*)(Drow + cb);
          }
        }
        // neighbor (i-1) at diag d-1: in-wave via DPP, wave boundary via nbv
        float sE = lane_shr1(eSelf);
        float sD = lane_shr1(dSelf);
        if (l0) { sE = nbv[k].x; sD = nbv[k].y; }
        const float e0 = eN2, e1 = sE, e2 = eSelf;
        const float sum = (e0 + e2) + e1;
        const float inv = __builtin_amdgcn_rcpf(sum);
        const float num  = fmaf(e0, dN2, fmaf(e1, sD, e2 * dSelf));
        const float numL = num * NL2E;            // off-chain pre-scale
        const float dddL = ddd * NL2E;            // off-chain pre-scale
        const float r2   = fmaf(inv, numL, dddL); // = -(ddd + inv*num)*log2e
        float newE = __builtin_amdgcn_exp2f(r2);
        newE = valid ? newE : 0.f;      // masks NaN from sum==0 (rcp(0)=inf)
        if (d == NM && t == N - 1) {    // final cell (512,512) — valid by def
          out[b] = fmaf(inv, num, ddd);                               // rlast
          out[BATCH + b] = sgA + inv * (e0 * sg0 + e1 * sg1 + e2 * sg2); // slast
        }
        // rotate carries; publish wave boundary
        eN2 = e1; dN2 = sD;
        eSelf = newE; dSelf = ddd;
        if (lane == 63 && w < 7)
          edge[w][d & (RING - 1)] = make_float2(newE, ddd);
      }
    }
    __syncthreads();
  }
}

extern "C" void kernel_launch(void* const* d_in, const int* in_sizes, int n_in,
                              void* d_out, int out_size, void* d_ws, size_t ws_size,
                              hipStream_t stream) {
  const float* D   = (const float*)d_in[0];
  const float* Sig = (const float*)d_in[1];
  float* out = (float*)d_out;
  softdtw_fwd<<<dim3(BATCH), dim3(512), 0, stream>>>(D, Sig, out);
}